// Round 6
// baseline (64.106 us; speedup 1.0000x reference)
//
#include <hip/hip_runtime.h>

constexpr int C   = 640;
constexpr int HW  = 25;
constexpr int PSTRIDE = 736;     // ws floats per gram block: 625 G + 100 moments + pad
constexpr int WSTRIDE = 704;     // ws floats per sample: 625 sim + 25 a + 25 b

__device__ __forceinline__ float rl(float x, int lane) {
  return __uint_as_float(__builtin_amdgcn_readlane(__float_as_uint(x), lane));
}

// ---------- Kernel 1: partial Gram (320 channels) + moments, transposed LDS ----------
// LDS: st[mat][k][c] with c contiguous (160 floats/row), quad-swizzled: quad cq stored at cq^(k&7).
__global__ __launch_bounds__(256, 4) void emd_gram(
    const float* __restrict__ support, const float* __restrict__ query,
    float* __restrict__ part)
{
  const int bid = blockIdx.x;
  const int n = bid >> 1, h = bid & 1;
  const int tid = threadIdx.x;

  __shared__ float st[8000] __attribute__((aligned(16)));  // 32000 B; tail/Gp aliased below

  const float* Qg = query   + (size_t)n * (C * HW) + (size_t)h * (320 * HW);
  const float* Sg = support + (size_t)n * (C * HW) + (size_t)h * (320 * HW);

  float acc[5][5] = {{0.f}};
  const int tile = tid % 25, grp = tid / 25;          // grp 0..9 (tid<250)
  const int u0 = (tile / 5) * 5, v0 = (tile % 5) * 5;
  const int kk  = tid % 25;                            // staging column (hw)
  const int cqm = tid / 25;                            // staging quad-group 0..9
  float mQ = 0.f, mQ2 = 0.f, mS = 0.f, mS2 = 0.f;      // register moments (fixed k=kk)

  for (int ch = 0; ch < 2; ++ch) {
    __syncthreads();   // previous chunk fully consumed
    if (tid < 250) {
      const float* Qc = Qg + ch * 4000;
      const float* Sc = Sg + ch * 4000;
      #pragma unroll
      for (int s = 0; s < 8; ++s) {
        const int cqf = cqm + s * 10;            // 0..79
        const int mat = (s < 4) ? 0 : 1;         // compile-time per s
        const int cq  = cqf - mat * 40;          // 0..39
        const float* gsrc = (mat ? Sc : Qc) + cq * 100 + kk;
        float x0 = gsrc[0], x1 = gsrc[25], x2 = gsrc[50], x3 = gsrc[75];
        if (mat == 0) {
          mQ += (x0 + x1) + (x2 + x3);
          mQ2 = fmaf(x0, x0, mQ2); mQ2 = fmaf(x1, x1, mQ2);
          mQ2 = fmaf(x2, x2, mQ2); mQ2 = fmaf(x3, x3, mQ2);
        } else {
          mS += (x0 + x1) + (x2 + x3);
          mS2 = fmaf(x0, x0, mS2); mS2 = fmaf(x1, x1, mS2);
          mS2 = fmaf(x2, x2, mS2); mS2 = fmaf(x3, x3, mS2);
        }
        float4 val = {x0, x1, x2, x3};
        *reinterpret_cast<float4*>(st + mat * 4000 + kk * 160 + ((cq ^ (kk & 7)) << 2)) = val;
      }
    }
    __syncthreads();

    if (tid < 250) {
      #pragma unroll
      for (int step = 0; step < 4; ++step) {
        const int cq = grp * 4 + step;
        float4 q[5], s[5];
        #pragma unroll
        for (int i = 0; i < 5; ++i) {
          const int rq = u0 + i;
          q[i] = *reinterpret_cast<const float4*>(st + rq * 160 + ((cq ^ (rq & 7)) << 2));
          const int rs = v0 + i;
          s[i] = *reinterpret_cast<const float4*>(st + 4000 + rs * 160 + ((cq ^ (rs & 7)) << 2));
        }
        #pragma unroll
        for (int i = 0; i < 5; ++i)
          #pragma unroll
          for (int j = 0; j < 5; ++j) {
            acc[i][j] = fmaf(q[i].x, s[j].x, acc[i][j]);
            acc[i][j] = fmaf(q[i].y, s[j].y, acc[i][j]);
            acc[i][j] = fmaf(q[i].z, s[j].z, acc[i][j]);
            acc[i][j] = fmaf(q[i].w, s[j].w, acc[i][j]);
          }
      }
    }
  }
  __syncthreads();   // staging reads done; st reusable: [0,6250) Gp, [6400,7424) moment partials

  if (tid < 250) {
    #pragma unroll
    for (int i = 0; i < 5; ++i)
      #pragma unroll
      for (int j = 0; j < 5; ++j)
        st[grp * 625 + (u0 + i) * 25 + (v0 + j)] = acc[i][j];
    st[6400 + 0 * 256 + tid] = mQ;
    st[6400 + 1 * 256 + tid] = mQ2;
    st[6400 + 2 * 256 + tid] = mS;
    st[6400 + 3 * 256 + tid] = mS2;
  }
  __syncthreads();

  float* w = part + (size_t)bid * PSTRIDE;
  for (int p = tid; p < 625; p += 256) {
    float g = 0.f;
    #pragma unroll
    for (int gg = 0; gg < 10; ++gg) g += st[gg * 625 + p];
    w[p] = g;
  }
  if (tid < 100) {
    const int vt = tid / 25, col = tid % 25;
    float s = 0.f;
    #pragma unroll
    for (int m = 0; m < 10; ++m) s += st[6400 + vt * 256 + m * 25 + col];
    w[625 + vt * 25 + col] = s;    // order: sQ, ssQ, sS, ssS
  }
}

// ---------- Kernel 2: combine halves -> sim + marginals ----------
__global__ __launch_bounds__(256) void emd_combine(
    const float* __restrict__ part, float* __restrict__ sink)
{
  const int n = blockIdx.x, tid = threadIdx.x;
  const float* p0 = part + (size_t)(2 * n) * PSTRIDE;
  const float* p1 = part + (size_t)(2 * n + 1) * PSTRIDE;
  float* w = sink + (size_t)n * WSTRIDE;

  __shared__ float G[625];
  __shared__ float sQ[25], sS[25], ssQ[25], ssS[25];
  __shared__ float am[25], bm[25], nq[25], ns[25];
  __shared__ float scal[2];

  for (int p = tid; p < 625; p += 256) G[p] = p0[p] + p1[p];
  if (tid < 50) {
    int mat = tid / 25, col = tid % 25;
    int ob = 625 + mat * 50 + col;              // mat0: sQ@625, ssQ@650; mat1: sS@675, ssS@700
    float s  = p0[ob]      + p1[ob];
    float ss = p0[ob + 25] + p1[ob + 25];
    if (mat == 0) { sQ[col] = s; ssQ[col] = ss; }
    else          { sS[col] = s; ssS[col] = ss; }
  }
  __syncthreads();

  if (tid < 25) {
    float s = 0.f;
    #pragma unroll
    for (int j = 0; j < 25; ++j) s += G[tid * 25 + j];
    am[tid] = fmaxf(s * (1.f / 25.f), 0.f) + 0.001f + 1e-5f;
    float var = ssQ[tid] - sQ[tid] * sQ[tid] * (1.f / C);
    nq[tid] = fmaxf(sqrtf(fmaxf(var, 0.f)), 1e-8f);
  } else if (tid >= 32 && tid < 57) {
    int v = tid - 32;
    float s = 0.f;
    #pragma unroll
    for (int u = 0; u < 25; ++u) s += G[u * 25 + v];
    bm[v] = fmaxf(s * (1.f / 25.f), 0.f) + 0.001f + 1e-5f;
    float var = ssS[v] - sS[v] * sS[v] * (1.f / C);
    ns[v] = fmaxf(sqrtf(fmaxf(var, 0.f)), 1e-8f);
  }
  __syncthreads();
  if (tid == 0)  { float s = 0.f; for (int i = 0; i < 25; ++i) s += am[i]; scal[0] = 25.f / s; }
  if (tid == 64) { float s = 0.f; for (int i = 0; i < 25; ++i) s += bm[i]; scal[1] = 25.f / s; }
  __syncthreads();

  if (tid < 25)                    w[625 + tid]      = am[tid] * scal[0];
  else if (tid >= 32 && tid < 57)  w[650 + tid - 32] = bm[tid - 32] * scal[1];

  for (int p = tid; p < 625; p += 256) {
    int u = p / 25, v = p % 25;
    float cov = G[p] - sQ[u] * sS[v] * (1.f / C);
    w[p] = cov / (nq[u] * ns[v]);
  }
}

// ---------- Kernel 3: Sinkhorn + reduction, one wave/sample ----------
__global__ __launch_bounds__(64) void emd_sink(
    const float* __restrict__ sink, float* __restrict__ out)
{
  const int n    = blockIdx.x;
  const int lane = threadIdx.x;
  const int u    = (lane < 25) ? lane : 24;
  const float* w = sink + (size_t)n * WSTRIDE;

  float simr[25], Krow[25], Kcol[25];
  #pragma unroll
  for (int j = 0; j < 25; ++j) simr[j] = w[u * 25 + j];
  #pragma unroll
  for (int j = 0; j < 25; ++j) Kcol[j] = __expf(-20.f * (1.f - w[j * 25 + u]));
  #pragma unroll
  for (int j = 0; j < 25; ++j) Krow[j] = __expf(-20.f * (1.f - simr[j]));
  const float a_u = w[625 + u], b_u = w[650 + u];

  float vv = 1.0f, uu = 0.0f, vold = 1.0f;
  #pragma unroll 1
  for (int it = 0; it < 100; ++it) {
    float s0 = 0, s1 = 0, s2 = 0, s3 = 0, s4 = 0;
    #pragma unroll
    for (int j = 0; j < 25; j += 5) {
      s0 = fmaf(Krow[j + 0], rl(vv, j + 0), s0);
      s1 = fmaf(Krow[j + 1], rl(vv, j + 1), s1);
      s2 = fmaf(Krow[j + 2], rl(vv, j + 2), s2);
      s3 = fmaf(Krow[j + 3], rl(vv, j + 3), s3);
      s4 = fmaf(Krow[j + 4], rl(vv, j + 4), s4);
    }
    uu = a_u * __builtin_amdgcn_rcpf(((((s0 + s1) + (s2 + s3)) + s4) + 1e-30f));

    s0 = s1 = s2 = s3 = s4 = 0;
    #pragma unroll
    for (int j = 0; j < 25; j += 5) {
      s0 = fmaf(Kcol[j + 0], rl(uu, j + 0), s0);
      s1 = fmaf(Kcol[j + 1], rl(uu, j + 1), s1);
      s2 = fmaf(Kcol[j + 2], rl(uu, j + 2), s2);
      s3 = fmaf(Kcol[j + 3], rl(uu, j + 3), s3);
      s4 = fmaf(Kcol[j + 4], rl(uu, j + 4), s4);
    }
    vv = b_u * __builtin_amdgcn_rcpf(((((s0 + s1) + (s2 + s3)) + s4) + 1e-30f));

    if ((it & 7) == 7) {
      bool conv = fabsf(vv - vold) <= 1e-5f * fabsf(vv);
      if (__all(conv)) break;
      vold = vv;
    }
  }
  {
    float s0 = 0, s1 = 0, s2 = 0, s3 = 0, s4 = 0;
    #pragma unroll
    for (int j = 0; j < 25; j += 5) {
      s0 = fmaf(Krow[j + 0], rl(vv, j + 0), s0);
      s1 = fmaf(Krow[j + 1], rl(vv, j + 1), s1);
      s2 = fmaf(Krow[j + 2], rl(vv, j + 2), s2);
      s3 = fmaf(Krow[j + 3], rl(vv, j + 3), s3);
      s4 = fmaf(Krow[j + 4], rl(vv, j + 4), s4);
    }
    uu = a_u * __builtin_amdgcn_rcpf(((((s0 + s1) + (s2 + s3)) + s4) + 1e-30f));
  }

  float pr = 0.f;
  if (lane < 25) {
    float t0 = 0.f;
    #pragma unroll
    for (int j = 0; j < 25; ++j)
      t0 = fmaf(simr[j] * Krow[j], rl(vv, j), t0);
    pr = uu * t0;
  }
  #pragma unroll
  for (int off = 32; off; off >>= 1) pr += __shfl_xor(pr, off);
  if (lane == 0) out[n] = pr * 0.5f;   // TEMPERATURE/hw = 12.5/25
}

extern "C" void kernel_launch(void* const* d_in, const int* in_sizes, int n_in,
                              void* d_out, int out_size, void* d_ws, size_t ws_size,
                              hipStream_t stream) {
  const float* support = (const float*)d_in[0];
  const float* query   = (const float*)d_in[1];
  float* out = (float*)d_out;
  const int N = in_sizes[0] / (C * HW);   // 600
  float* partbuf = (float*)d_ws;
  float* sinkbuf = partbuf + (size_t)(2 * N) * PSTRIDE;
  emd_gram   <<<dim3(2 * N), dim3(256), 0, stream>>>(support, query, partbuf);
  emd_combine<<<dim3(N),     dim3(256), 0, stream>>>(partbuf, sinkbuf);
  emd_sink   <<<dim3(N),     dim3(64),  0, stream>>>(sinkbuf, out);
}

// Round 7
// 30.787 us; speedup vs baseline: 2.0822x; 2.0822x over previous
//
#include <hip/hip_runtime.h>

typedef short bf16x8 __attribute__((ext_vector_type(8)));
typedef float f32x4  __attribute__((ext_vector_type(4)));

constexpr int C  = 640;
constexpr int HW = 25;
constexpr int CHUNK  = 128;   // channels per LDS chunk
constexpr int NCHUNK = 5;

__device__ __forceinline__ float rl(float x, int lane) {
  return __uint_as_float(__builtin_amdgcn_readlane(__float_as_uint(x), lane));
}

__device__ __forceinline__ void split_bf16(float x, unsigned& h, unsigned& l) {
  unsigned u = __float_as_uint(x);
  unsigned hb = (u + 0x7FFFu + ((u >> 16) & 1u)) >> 16;
  float hf = __uint_as_float(hb << 16);
  float lo = x - hf;
  unsigned ul = __float_as_uint(lo);
  unsigned lb = (ul + 0x7FFFu + ((ul >> 16) & 1u)) >> 16;
  h = hb; l = lb;
}

// LDS halfword layout: plane = mat*2+part (Qhi,Qlo,Shi,Slo), [32 rows][128 ch],
// byte addr ((plane*32+r)*128 + c)*2, XOR-swizzled by ((r&15)<<4).
__global__ __launch_bounds__(256) void emd_fused(
    const float* __restrict__ support, const float* __restrict__ query,
    float* __restrict__ out)
{
  const int n = blockIdx.x, tid = threadIdx.x;

  __shared__ __attribute__((aligned(16))) unsigned short planes[4 * 32 * CHUNK]; // 32 KB
  __shared__ float G[625];
  __shared__ float scr[4][200];
  __shared__ float sQv[25], sSv[25], nqv[25], nsv[25], amv[25], bmv[25], scal[2];

  const float* Qg = query   + (size_t)n * (C * HW);
  const float* Sg = support + (size_t)n * (C * HW);

  // zero pad rows 25..31 of each plane (never rewritten; frag reads touch them)
  for (int g = tid; g < 448; g += 256) {
    int pl = g / 112, rem = g % 112;
    int r = 25 + rem / 16, cq = rem % 16;
    *reinterpret_cast<uint4*>(reinterpret_cast<char*>(planes) +
                              ((pl * 32 + r) * CHUNK + cq * 8) * 2) = make_uint4(0, 0, 0, 0);
  }

  const int k = tid % 25;                 // spatial node index (staging, tid<200)
  f32x4 acc[2][2];
  {
    f32x4 z = {0.f, 0.f, 0.f, 0.f};
    acc[0][0] = z; acc[0][1] = z; acc[1][0] = z; acc[1][1] = z;
  }
  float mQ = 0.f, mQ2 = 0.f, mS = 0.f, mS2 = 0.f;

  for (int ch = 0; ch < NCHUNK; ++ch) {
    if (ch) __syncthreads();             // prev chunk's MFMA done
    if (tid < 200) {
      #pragma unroll
      for (int p = 0; p < 4; ++p) {
        const int gm = tid + (p & 1) * 200;      // k = gm%25 == tid%25
        const int cg = gm / 25;                   // 0..15
        const int mat = p >> 1;
        const float* src = (mat ? Sg : Qg) + ((size_t)ch * CHUNK + cg * 8) * HW + k;
        float x[8];
        #pragma unroll
        for (int j = 0; j < 8; ++j) x[j] = src[j * 25];
        if (mat == 0) {
          #pragma unroll
          for (int j = 0; j < 8; ++j) { mQ += x[j]; mQ2 = fmaf(x[j], x[j], mQ2); }
        } else {
          #pragma unroll
          for (int j = 0; j < 8; ++j) { mS += x[j]; mS2 = fmaf(x[j], x[j], mS2); }
        }
        unsigned hwd[4], lwd[4];
        #pragma unroll
        for (int jj = 0; jj < 4; ++jj) {
          unsigned h0, l0, h1, l1;
          split_bf16(x[2 * jj], h0, l0);
          split_bf16(x[2 * jj + 1], h1, l1);
          hwd[jj] = h0 | (h1 << 16);
          lwd[jj] = l0 | (l1 << 16);
        }
        const int xo = (k & 15) << 4;
        char* pb = reinterpret_cast<char*>(planes);
        int bh = ((((mat * 2 + 0) * 32 + k) * CHUNK + cg * 8) * 2) ^ xo;
        int bl = ((((mat * 2 + 1) * 32 + k) * CHUNK + cg * 8) * 2) ^ xo;
        *reinterpret_cast<uint4*>(pb + bh) = make_uint4(hwd[0], hwd[1], hwd[2], hwd[3]);
        *reinterpret_cast<uint4*>(pb + bl) = make_uint4(lwd[0], lwd[1], lwd[2], lwd[3]);
      }
    }
    __syncthreads();
    if (tid < 64) {                       // wave 0: 4 K-steps x (8 b128 + 12 MFMA)
      const char* pb = reinterpret_cast<const char*>(planes);
      #pragma unroll
      for (int s = 0; s < 4; ++s) {
        const int cb = (s * 32 + ((tid >> 4) * 8)) * 2;   // byte offset within row
        bf16x8 Ah[2], Al[2], Bh[2], Bl[2];
        #pragma unroll
        for (int tr = 0; tr < 2; ++tr) {
          const int r = (tid & 15) + 16 * tr;
          const int xo = (r & 15) << 4;
          Ah[tr] = *reinterpret_cast<const bf16x8*>(pb + ((((0 * 32 + r) * CHUNK) * 2 + cb) ^ xo));
          Al[tr] = *reinterpret_cast<const bf16x8*>(pb + ((((1 * 32 + r) * CHUNK) * 2 + cb) ^ xo));
          Bh[tr] = *reinterpret_cast<const bf16x8*>(pb + ((((2 * 32 + r) * CHUNK) * 2 + cb) ^ xo));
          Bl[tr] = *reinterpret_cast<const bf16x8*>(pb + ((((3 * 32 + r) * CHUNK) * 2 + cb) ^ xo));
        }
        #pragma unroll
        for (int tr = 0; tr < 2; ++tr)
          #pragma unroll
          for (int tc = 0; tc < 2; ++tc) {
            acc[tr][tc] = __builtin_amdgcn_mfma_f32_16x16x32_bf16(Ah[tr], Bh[tc], acc[tr][tc], 0, 0, 0);
            acc[tr][tc] = __builtin_amdgcn_mfma_f32_16x16x32_bf16(Ah[tr], Bl[tc], acc[tr][tc], 0, 0, 0);
            acc[tr][tc] = __builtin_amdgcn_mfma_f32_16x16x32_bf16(Al[tr], Bh[tc], acc[tr][tc], 0, 0, 0);
          }
      }
    }
  }

  // G to LDS (C/D layout: col=lane&15, row=(lane>>4)*4+reg — m89-verified)
  if (tid < 64) {
    #pragma unroll
    for (int tr = 0; tr < 2; ++tr)
      #pragma unroll
      for (int tc = 0; tc < 2; ++tc)
        #pragma unroll
        for (int i = 0; i < 4; ++i) {
          int u = tr * 16 + (tid >> 4) * 4 + i;
          int v = tc * 16 + (tid & 15);
          if (u < 25 && v < 25) G[u * 25 + v] = acc[tr][tc][i];
        }
  }
  if (tid < 200) { scr[0][tid] = mQ; scr[1][tid] = mQ2; scr[2][tid] = mS; scr[3][tid] = mS2; }
  __syncthreads();

  if (tid < 25) {
    float s = 0.f, ss = 0.f;
    #pragma unroll
    for (int i = 0; i < 8; ++i) { s += scr[0][tid + 25 * i]; ss += scr[1][tid + 25 * i]; }
    sQv[tid] = s;
    float var = ss - s * s * (1.f / C);
    nqv[tid] = fmaxf(sqrtf(fmaxf(var, 0.f)), 1e-8f);
    float rs = 0.f;
    #pragma unroll
    for (int j = 0; j < 25; ++j) rs += G[tid * 25 + j];
    amv[tid] = fmaxf(rs * (1.f / 25.f), 0.f) + 0.001f + 1e-5f;
  } else if (tid >= 32 && tid < 57) {
    int v = tid - 32;
    float s = 0.f, ss = 0.f;
    #pragma unroll
    for (int i = 0; i < 8; ++i) { s += scr[2][v + 25 * i]; ss += scr[3][v + 25 * i]; }
    sSv[v] = s;
    float var = ss - s * s * (1.f / C);
    nsv[v] = fmaxf(sqrtf(fmaxf(var, 0.f)), 1e-8f);
    float cs = 0.f;
    #pragma unroll
    for (int u = 0; u < 25; ++u) cs += G[u * 25 + v];
    bmv[v] = fmaxf(cs * (1.f / 25.f), 0.f) + 0.001f + 1e-5f;
  }
  __syncthreads();
  if (tid == 0)  { float s = 0.f; for (int i = 0; i < 25; ++i) s += amv[i]; scal[0] = 25.f / s; }
  if (tid == 64) { float s = 0.f; for (int i = 0; i < 25; ++i) s += bmv[i]; scal[1] = 25.f / s; }
  __syncthreads();
  for (int p = tid; p < 625; p += 256) {     // sim in place
    int u = p / 25, v = p % 25;
    float cov = G[p] - sQv[u] * sSv[v] * (1.f / C);
    G[p] = cov / (nqv[u] * nsv[v]);
  }
  __syncthreads();

  if (tid >= 64) return;                     // Sinkhorn on wave 0
  const int lane = tid;
  const int u = (lane < 25) ? lane : 24;
  float simr[25], Krow[25], Kcol[25];
  #pragma unroll
  for (int j = 0; j < 25; ++j) simr[j] = G[u * 25 + j];
  #pragma unroll
  for (int j = 0; j < 25; ++j) Kcol[j] = __expf(-20.f * (1.f - G[j * 25 + u]));
  #pragma unroll
  for (int j = 0; j < 25; ++j) Krow[j] = __expf(-20.f * (1.f - simr[j]));
  const float a_u = amv[u] * scal[0], b_u = bmv[u] * scal[1];

  float vv = 1.0f, uu = 0.0f, vold = 1.0f;
  #pragma unroll 1
  for (int it = 0; it < 100; ++it) {
    float s0 = 0, s1 = 0, s2 = 0, s3 = 0, s4 = 0;
    #pragma unroll
    for (int j = 0; j < 25; j += 5) {
      s0 = fmaf(Krow[j + 0], rl(vv, j + 0), s0);
      s1 = fmaf(Krow[j + 1], rl(vv, j + 1), s1);
      s2 = fmaf(Krow[j + 2], rl(vv, j + 2), s2);
      s3 = fmaf(Krow[j + 3], rl(vv, j + 3), s3);
      s4 = fmaf(Krow[j + 4], rl(vv, j + 4), s4);
    }
    uu = a_u * __builtin_amdgcn_rcpf(((((s0 + s1) + (s2 + s3)) + s4) + 1e-30f));

    s0 = s1 = s2 = s3 = s4 = 0;
    #pragma unroll
    for (int j = 0; j < 25; j += 5) {
      s0 = fmaf(Kcol[j + 0], rl(uu, j + 0), s0);
      s1 = fmaf(Kcol[j + 1], rl(uu, j + 1), s1);
      s2 = fmaf(Kcol[j + 2], rl(uu, j + 2), s2);
      s3 = fmaf(Kcol[j + 3], rl(uu, j + 3), s3);
      s4 = fmaf(Kcol[j + 4], rl(uu, j + 4), s4);
    }
    vv = b_u * __builtin_amdgcn_rcpf(((((s0 + s1) + (s2 + s3)) + s4) + 1e-30f));

    if ((it & 7) == 7) {
      bool conv = fabsf(vv - vold) <= 1e-5f * fabsf(vv);
      if (__all(conv)) break;
      vold = vv;
    }
  }
  {
    float s0 = 0, s1 = 0, s2 = 0, s3 = 0, s4 = 0;
    #pragma unroll
    for (int j = 0; j < 25; j += 5) {
      s0 = fmaf(Krow[j + 0], rl(vv, j + 0), s0);
      s1 = fmaf(Krow[j + 1], rl(vv, j + 1), s1);
      s2 = fmaf(Krow[j + 2], rl(vv, j + 2), s2);
      s3 = fmaf(Krow[j + 3], rl(vv, j + 3), s3);
      s4 = fmaf(Krow[j + 4], rl(vv, j + 4), s4);
    }
    uu = a_u * __builtin_amdgcn_rcpf(((((s0 + s1) + (s2 + s3)) + s4) + 1e-30f));
  }

  float pr = 0.f;
  if (lane < 25) {
    float t0 = 0.f;
    #pragma unroll
    for (int j = 0; j < 25; ++j)
      t0 = fmaf(simr[j] * Krow[j], rl(vv, j), t0);
    pr = uu * t0;
  }
  #pragma unroll
  for (int off = 32; off; off >>= 1) pr += __shfl_xor(pr, off);
  if (lane == 0) out[n] = pr * 0.5f;   // TEMPERATURE/hw = 12.5/25
}

extern "C" void kernel_launch(void* const* d_in, const int* in_sizes, int n_in,
                              void* d_out, int out_size, void* d_ws, size_t ws_size,
                              hipStream_t stream) {
  const float* support = (const float*)d_in[0];
  const float* query   = (const float*)d_in[1];
  float* out = (float*)d_out;
  const int N = in_sizes[0] / (C * HW);   // 600
  emd_fused<<<dim3(N), dim3(256), 0, stream>>>(support, query, out);
}

// Round 8
// 25.804 us; speedup vs baseline: 2.4843x; 1.1931x over previous
//
#include <hip/hip_runtime.h>

typedef short bf16x8 __attribute__((ext_vector_type(8)));
typedef float f32x4  __attribute__((ext_vector_type(4)));

constexpr int C  = 640;
constexpr int HW = 25;

__device__ __forceinline__ float rl(float x, int lane) {
  return __uint_as_float(__builtin_amdgcn_readlane(__float_as_uint(x), lane));
}

// pack 2 fp32 -> (hi-bf16 pair, lo-bf16 pair), truncating split:
// hi = trunc_bf16(x); lo = trunc_bf16(x - hi)  (x-hi exact in fp32)
__device__ __forceinline__ void packpair(float x0, float x1, unsigned& h, unsigned& l) {
  unsigned u0 = __float_as_uint(x0), u1 = __float_as_uint(x1);
  h = __builtin_amdgcn_perm(u1, u0, 0x07060302u);      // [u1.hi16 : u0.hi16]
  float l0 = x0 - __uint_as_float(u0 & 0xFFFF0000u);
  float l1 = x1 - __uint_as_float(u1 & 0xFFFF0000u);
  l = __builtin_amdgcn_perm(__float_as_uint(l1), __float_as_uint(l0), 0x07060302u);
}

__global__ __launch_bounds__(256) void emd_fused(
    const float* __restrict__ support, const float* __restrict__ query,
    float* __restrict__ out)
{
  const int n = blockIdx.x, tid = threadIdx.x;
  const int wid = tid >> 6, lane = tid & 63;
  const int lg = lane >> 4, lr = lane & 15;   // channel sub-group, row-within-16

  __shared__ float accbuf[4][64][16];   // 16 KB
  __shared__ float mombuf[4][8][64];    // 8 KB
  __shared__ float G[625];
  __shared__ float sQv[25], sSv[25], nqv[25], nsv[25], amv[25], bmv[25], scal[2];

  const float* Qg = query   + (size_t)n * C * HW;
  const float* Sg = support + (size_t)n * C * HW;

  f32x4 acc[2][2];
  {
    f32x4 z = {0.f, 0.f, 0.f, 0.f};
    acc[0][0] = z; acc[0][1] = z; acc[1][0] = z; acc[1][1] = z;
  }
  float mq[2] = {0.f, 0.f}, mq2[2] = {0.f, 0.f};
  float ms[2] = {0.f, 0.f}, ms2[2] = {0.f, 0.f};

  // ---- Gram via MFMA, fragments loaded straight from global (no LDS, no barriers) ----
  #pragma unroll 1
  for (int s = 0; s < 5; ++s) {
    const int c0 = wid * 160 + s * 32 + lg * 8;   // 8 channels for this lane-group
    const float* qb = Qg + c0 * HW;
    const float* sb = Sg + c0 * HW;
    bf16x8 Ah[2], Al[2], Bh[2], Bl[2];
    #pragma unroll
    for (int t = 0; t < 2; ++t) {
      const int row = t * 16 + lr;
      const bool ok = row < 25;
      float xq[8], xs[8];
      #pragma unroll
      for (int j = 0; j < 8; ++j) {
        xq[j] = ok ? qb[j * HW + row] : 0.f;
        xs[j] = ok ? sb[j * HW + row] : 0.f;
      }
      #pragma unroll
      for (int j = 0; j < 8; ++j) {
        mq[t] += xq[j]; mq2[t] = fmaf(xq[j], xq[j], mq2[t]);
        ms[t] += xs[j]; ms2[t] = fmaf(xs[j], xs[j], ms2[t]);
      }
      union { unsigned u[4]; bf16x8 v; } ah, al, bh, bl;
      #pragma unroll
      for (int jj = 0; jj < 4; ++jj) {
        packpair(xq[2 * jj], xq[2 * jj + 1], ah.u[jj], al.u[jj]);
        packpair(xs[2 * jj], xs[2 * jj + 1], bh.u[jj], bl.u[jj]);
      }
      Ah[t] = ah.v; Al[t] = al.v; Bh[t] = bh.v; Bl[t] = bl.v;
    }
    #pragma unroll
    for (int tr = 0; tr < 2; ++tr)
      #pragma unroll
      for (int tc = 0; tc < 2; ++tc) {
        acc[tr][tc] = __builtin_amdgcn_mfma_f32_16x16x32_bf16(Ah[tr], Bh[tc], acc[tr][tc], 0, 0, 0);
        acc[tr][tc] = __builtin_amdgcn_mfma_f32_16x16x32_bf16(Ah[tr], Bl[tc], acc[tr][tc], 0, 0, 0);
        acc[tr][tc] = __builtin_amdgcn_mfma_f32_16x16x32_bf16(Al[tr], Bh[tc], acc[tr][tc], 0, 0, 0);
      }
  }

  // dump per-wave partials
  #pragma unroll
  for (int tr = 0; tr < 2; ++tr)
    #pragma unroll
    for (int tc = 0; tc < 2; ++tc)
      *reinterpret_cast<f32x4*>(&accbuf[wid][lane][(tr * 2 + tc) * 4]) = acc[tr][tc];
  mombuf[wid][0][lane] = mq[0];  mombuf[wid][1][lane] = mq[1];
  mombuf[wid][2][lane] = mq2[0]; mombuf[wid][3][lane] = mq2[1];
  mombuf[wid][4][lane] = ms[0];  mombuf[wid][5][lane] = ms[1];
  mombuf[wid][6][lane] = ms2[0]; mombuf[wid][7][lane] = ms2[1];
  __syncthreads();

  // cross-wave acc reduce -> G (C/D layout col=lane&15, row=(lane>>4)*4+i — m89-verified)
  if (tid < 64) {
    #pragma unroll
    for (int q = 0; q < 4; ++q) {
      f32x4 rsum = *reinterpret_cast<const f32x4*>(&accbuf[0][lane][q * 4]);
      #pragma unroll
      for (int w = 1; w < 4; ++w)
        rsum += *reinterpret_cast<const f32x4*>(&accbuf[w][lane][q * 4]);
      const int tr = q >> 1, tc = q & 1;
      #pragma unroll
      for (int i = 0; i < 4; ++i) {
        int u = tr * 16 + (lane >> 4) * 4 + i;
        int v = tc * 16 + (lane & 15);
        if (u < 25 && v < 25) G[u * 25 + v] = rsum[i];
      }
    }
  }
  __syncthreads();

  // moments + marginals
  if (tid < 25) {
    const int t = (tid < 16) ? 0 : 1, rr = tid - t * 16;
    float s = 0.f, ss = 0.f;
    #pragma unroll
    for (int w = 0; w < 4; ++w)
      #pragma unroll
      for (int gg = 0; gg < 4; ++gg) {
        s  += mombuf[w][0 + t][gg * 16 + rr];
        ss += mombuf[w][2 + t][gg * 16 + rr];
      }
    sQv[tid] = s;
    float var = ss - s * s * (1.f / C);
    nqv[tid] = fmaxf(sqrtf(fmaxf(var, 0.f)), 1e-8f);
    float rs = 0.f;
    #pragma unroll
    for (int j = 0; j < 25; ++j) rs += G[tid * 25 + j];
    amv[tid] = fmaxf(rs * (1.f / 25.f), 0.f) + 0.001f + 1e-5f;
  } else if (tid >= 32 && tid < 57) {
    const int v = tid - 32;
    const int t = (v < 16) ? 0 : 1, rr = v - t * 16;
    float s = 0.f, ss = 0.f;
    #pragma unroll
    for (int w = 0; w < 4; ++w)
      #pragma unroll
      for (int gg = 0; gg < 4; ++gg) {
        s  += mombuf[w][4 + t][gg * 16 + rr];
        ss += mombuf[w][6 + t][gg * 16 + rr];
      }
    sSv[v] = s;
    float var = ss - s * s * (1.f / C);
    nsv[v] = fmaxf(sqrtf(fmaxf(var, 0.f)), 1e-8f);
    float cs = 0.f;
    #pragma unroll
    for (int u = 0; u < 25; ++u) cs += G[u * 25 + v];
    bmv[v] = fmaxf(cs * (1.f / 25.f), 0.f) + 0.001f + 1e-5f;
  }
  __syncthreads();
  if (tid == 0)  { float s = 0.f; for (int i = 0; i < 25; ++i) s += amv[i]; scal[0] = 25.f / s; }
  if (tid == 64) { float s = 0.f; for (int i = 0; i < 25; ++i) s += bmv[i]; scal[1] = 25.f / s; }
  __syncthreads();
  for (int p = tid; p < 625; p += 256) {     // sim in place
    int u = p / 25, v = p % 25;
    float cov = G[p] - sQv[u] * sSv[v] * (1.f / C);
    G[p] = cov / (nqv[u] * nsv[v]);
  }
  __syncthreads();

  if (tid >= 64) return;                     // Sinkhorn on wave 0
  const int u = (tid < 25) ? tid : 24;
  float simr[25], Krow[25], Kcol[25];
  #pragma unroll
  for (int j = 0; j < 25; ++j) simr[j] = G[u * 25 + j];
  #pragma unroll
  for (int j = 0; j < 25; ++j) Kcol[j] = __expf(-20.f * (1.f - G[j * 25 + u]));
  #pragma unroll
  for (int j = 0; j < 25; ++j) Krow[j] = __expf(-20.f * (1.f - simr[j]));
  const float a_u = amv[u] * scal[0], b_u = bmv[u] * scal[1];

  float vv = 1.0f, uu = 0.0f, vold = 1.0f;
  #pragma unroll 1
  for (int it = 0; it < 100; ++it) {
    float s0 = 0, s1 = 0, s2 = 0, s3 = 0, s4 = 0;
    #pragma unroll
    for (int j = 0; j < 25; j += 5) {
      s0 = fmaf(Krow[j + 0], rl(vv, j + 0), s0);
      s1 = fmaf(Krow[j + 1], rl(vv, j + 1), s1);
      s2 = fmaf(Krow[j + 2], rl(vv, j + 2), s2);
      s3 = fmaf(Krow[j + 3], rl(vv, j + 3), s3);
      s4 = fmaf(Krow[j + 4], rl(vv, j + 4), s4);
    }
    uu = a_u * __builtin_amdgcn_rcpf(((((s0 + s1) + (s2 + s3)) + s4) + 1e-30f));

    s0 = s1 = s2 = s3 = s4 = 0;
    #pragma unroll
    for (int j = 0; j < 25; j += 5) {
      s0 = fmaf(Kcol[j + 0], rl(uu, j + 0), s0);
      s1 = fmaf(Kcol[j + 1], rl(uu, j + 1), s1);
      s2 = fmaf(Kcol[j + 2], rl(uu, j + 2), s2);
      s3 = fmaf(Kcol[j + 3], rl(uu, j + 3), s3);
      s4 = fmaf(Kcol[j + 4], rl(uu, j + 4), s4);
    }
    vv = b_u * __builtin_amdgcn_rcpf(((((s0 + s1) + (s2 + s3)) + s4) + 1e-30f));

    if ((it & 3) == 3) {
      bool conv = fabsf(vv - vold) <= 1e-5f * fabsf(vv);
      if (__all(conv)) break;
      vold = vv;
    }
  }
  {
    float s0 = 0, s1 = 0, s2 = 0, s3 = 0, s4 = 0;
    #pragma unroll
    for (int j = 0; j < 25; j += 5) {
      s0 = fmaf(Krow[j + 0], rl(vv, j + 0), s0);
      s1 = fmaf(Krow[j + 1], rl(vv, j + 1), s1);
      s2 = fmaf(Krow[j + 2], rl(vv, j + 2), s2);
      s3 = fmaf(Krow[j + 3], rl(vv, j + 3), s3);
      s4 = fmaf(Krow[j + 4], rl(vv, j + 4), s4);
    }
    uu = a_u * __builtin_amdgcn_rcpf(((((s0 + s1) + (s2 + s3)) + s4) + 1e-30f));
  }

  float pr = 0.f;
  if (tid < 25) {
    float t0 = 0.f;
    #pragma unroll
    for (int j = 0; j < 25; ++j)
      t0 = fmaf(simr[j] * Krow[j], rl(vv, j), t0);
    pr = uu * t0;
  }
  #pragma unroll
  for (int off = 32; off; off >>= 1) pr += __shfl_xor(pr, off);
  if (tid == 0) out[n] = pr * 0.5f;   // TEMPERATURE/hw = 12.5/25
}

extern "C" void kernel_launch(void* const* d_in, const int* in_sizes, int n_in,
                              void* d_out, int out_size, void* d_ws, size_t ws_size,
                              hipStream_t stream) {
  const float* support = (const float*)d_in[0];
  const float* query   = (const float*)d_in[1];
  float* out = (float*)d_out;
  const int N = in_sizes[0] / (C * HW);   // 600
  emd_fused<<<dim3(N), dim3(256), 0, stream>>>(support, query, out);
}